// Round 3
// baseline (3122.581 us; speedup 1.0000x reference)
//
#include <hip/hip_runtime.h>
#include <hip/hip_bf16.h>

#define T_ 4
#define B_ 8
#define S_ 1024
#define D_ 768
#define BS_ (B_*S_)            // 8192
#define M_ (T_*B_*S_)          // 32768
#define BSD_ (B_*S_*D_)        // 6291456
#define LN_EPS 1e-5f
#define TAU 1e-3f

typedef unsigned short u16;
typedef unsigned char u8;
typedef unsigned long long u64;
typedef __bf16 bf16x8 __attribute__((ext_vector_type(8)));
typedef float f32x4 __attribute__((ext_vector_type(4)));

// ---- IF over x -> bitmask spikes + bf16 spikes, bit-exact vs np ----
__global__ __launch_bounds__(768)
void k_if_mask(const float* __restrict__ x, u64* __restrict__ Am, u16* __restrict__ Ab) {
    int bs = blockIdx.x;           // 8192 blocks
    int d = threadIdx.x;           // 768 threads
    int wv = d >> 6, lane = d & 63;
    float v = 0.f;
    for (int t = 0; t < T_; ++t) {
        v += x[(size_t)t * BSD_ + (size_t)bs * D_ + d];
        bool s = (v >= 1.0f);
        u64 m = __ballot(s);
        if (lane == 0) Am[((size_t)t * 12 + wv) * BS_ + bs] = m;
        Ab[(size_t)t * BSD_ + (size_t)bs * D_ + d] = s ? 0x3F80 : 0;
        if (s) v = 0.f;
    }
}

// ---- weight convert: Bt layout [N][K], hi/lo split for q/k/v; bf16 for wo ----
__global__ void k_wconv(const float* __restrict__ wq, const float* __restrict__ wk,
                        const float* __restrict__ wv, const float* __restrict__ wo,
                        u16* __restrict__ Whi, u16* __restrict__ Wlo, u16* __restrict__ Wo) {
    int idx = blockIdx.x * 256 + threadIdx.x;       // 4*768*768/256 = 9216 blocks
    int mat = idx / (D_ * D_);
    int r = idx % (D_ * D_);
    int n = r / D_;
    int k = r % D_;
    const float* src = (mat == 0) ? wq : (mat == 1) ? wk : (mat == 2) ? wv : wo;
    float w = src[k * D_ + n];
    __bf16 hi = (__bf16)w;
    u16 uhi = __builtin_bit_cast(u16, hi);
    if (mat == 3) { Wo[r] = uhi; return; }
    float lo = w - (float)hi;
    u16 ulo = __builtin_bit_cast(u16, (__bf16)lo);
    Whi[(size_t)mat * D_ * D_ + r] = uhi;
    Wlo[(size_t)mat * D_ * D_ + r] = ulo;
}

// ---- MFMA GEMM: C[M,N] = A[M,K] @ Bt[N,K]^T (accumulate over NMATS B's) ----
__device__ __forceinline__ void gload16(const void* g, void* l) {
    __builtin_amdgcn_global_load_lds(
        (const __attribute__((address_space(1))) unsigned int*)g,
        (__attribute__((address_space(3))) unsigned int*)l, 16, 0, 0);
}

template<int NMATS>
__global__ __launch_bounds__(256)
void k_gemm(const u16* __restrict__ A, const u16* __restrict__ B0,
            const u16* __restrict__ B1, float* __restrict__ C, int ntn, int N) {
    __shared__ __align__(16) u16 As[128 * 32];
    __shared__ __align__(16) u16 Bs[128 * 32];
    int bid = blockIdx.x;
    int bn = bid % ntn, bm = bid / ntn;
    int tid = threadIdx.x;
    int l = tid & 63, w = tid >> 6;
    int wr = w >> 1, wc = w & 1;
    int lan16 = l & 15, kh = l >> 4;

    f32x4 acc[4][4];
    #pragma unroll
    for (int m = 0; m < 4; ++m)
        #pragma unroll
        for (int n = 0; n < 4; ++n)
            #pragma unroll
            for (int r = 0; r < 4; ++r) acc[m][n][r] = 0.f;

    int arow = bm * 128 + (tid >> 2);
    int brow = bn * 128 + (tid >> 2);
    int colb = (tid & 3) * 8;
    char* ldsA = (char*)As + ((tid >> 6) << 10);
    char* ldsB = (char*)Bs + ((tid >> 6) << 10);

    for (int mat = 0; mat < NMATS; ++mat) {
        const u16* Bt = (mat == 0) ? B0 : B1;
        for (int kk = 0; kk < 768; kk += 32) {
            gload16(A  + (size_t)(arow     ) * 768 + kk + colb, ldsA);
            gload16(A  + (size_t)(arow + 64) * 768 + kk + colb, ldsA + 4096);
            gload16(Bt + (size_t)(brow     ) * 768 + kk + colb, ldsB);
            gload16(Bt + (size_t)(brow + 64) * 768 + kk + colb, ldsB + 4096);
            __syncthreads();
            bf16x8 af[4], bf[4];
            #pragma unroll
            for (int m = 0; m < 4; ++m)
                af[m] = *(const bf16x8*)((const char*)As + (wr * 64 + m * 16 + lan16) * 64 + kh * 16);
            #pragma unroll
            for (int n = 0; n < 4; ++n)
                bf[n] = *(const bf16x8*)((const char*)Bs + (wc * 64 + n * 16 + lan16) * 64 + kh * 16);
            #pragma unroll
            for (int m = 0; m < 4; ++m)
                #pragma unroll
                for (int n = 0; n < 4; ++n)
                    acc[m][n] = __builtin_amdgcn_mfma_f32_16x16x32_bf16(af[m], bf[n], acc[m][n], 0, 0, 0);
            __syncthreads();
        }
    }
    #pragma unroll
    for (int m = 0; m < 4; ++m)
        #pragma unroll
        for (int n = 0; n < 4; ++n)
            #pragma unroll
            for (int r = 0; r < 4; ++r) {
                int crow = bm * 128 + wr * 64 + m * 16 + kh * 4 + r;
                int ccol = bn * 128 + wc * 64 + n * 16 + lan16;
                C[(size_t)crow * N + ccol] = acc[m][n][r];
            }
}

// ---- LN (f64 mean/var) + IF -> u8 spikes, with boundary-margin flagging ----
__global__ __launch_bounds__(256)
void k_lnif(const float* __restrict__ Y, const float* __restrict__ g,
            const float* __restrict__ bt, u8* __restrict__ Sp, u8* __restrict__ flag) {
    #pragma clang fp contract(off)
    int row = blockIdx.x * 4 + (threadIdx.x >> 6);   // (b,s) 0..8191
    int lane = threadIdx.x & 63;
    float v[12];
    #pragma unroll
    for (int i = 0; i < 12; ++i) v[i] = 0.f;
    float gv[12], bv[12];
    #pragma unroll
    for (int i = 0; i < 12; ++i) { gv[i] = g[lane + 64*i]; bv[i] = bt[lane + 64*i]; }
    bool fl = false;
    for (int t = 0; t < T_; ++t) {
        size_t base = ((size_t)t * BS_ + row) * D_;
        float xv[12];
        double s = 0.0;
        #pragma unroll
        for (int i = 0; i < 12; ++i) { xv[i] = Y[base + lane + 64*i]; s += (double)xv[i]; }
        #pragma unroll
        for (int o = 1; o < 64; o <<= 1) s += __shfl_xor(s, o, 64);
        s = __shfl(s, 0, 64);
        float m = (float)(s / 768.0);
        float d[12];
        double q = 0.0;
        #pragma unroll
        for (int i = 0; i < 12; ++i) { d[i] = xv[i] - m; float sq = d[i]*d[i]; q += (double)sq; }
        #pragma unroll
        for (int o = 1; o < 64; o <<= 1) q += __shfl_xor(q, o, 64);
        q = __shfl(q, 0, 64);
        float var = (float)(q / 768.0);
        float inv = 1.0f / __fsqrt_rn(var + LN_EPS);
        #pragma unroll
        for (int i = 0; i < 12; ++i) {
            float yn = ((d[i] * inv) * gv[i]) + bv[i];
            v[i] += yn;
            fl = fl || (fabsf(v[i] - 1.0f) < TAU);
            bool sp = (v[i] >= 1.0f);
            Sp[base + lane + 64*i] = sp ? (u8)1 : (u8)0;
            if (sp) v[i] = 0.f;
        }
    }
    u64 bal = __ballot(fl);
    if (lane == 0 && bal != 0ull) flag[row] = 1;
}

// ---- repair: recompute flagged rows with exact bit-sequential GEMM + f64 LN ----
__global__ __launch_bounds__(768)
void k_repair(const u64* __restrict__ Am,
              const float* __restrict__ wq, const float* __restrict__ wk,
              const float* __restrict__ wv,
              const float* __restrict__ gq, const float* __restrict__ bq,
              const float* __restrict__ gk, const float* __restrict__ bk,
              const float* __restrict__ gv, const float* __restrict__ bv,
              u8* __restrict__ Qs, u8* __restrict__ Ks, u8* __restrict__ Vs,
              const u8* __restrict__ flags) {
    #pragma clang fp contract(off)
    int mat = blockIdx.y;
    int bs = blockIdx.x;
    if (!flags[(size_t)mat * BS_ + bs]) return;
    const float* W = (mat == 0) ? wq : (mat == 1) ? wk : wv;
    const float* g = (mat == 0) ? gq : (mat == 1) ? gk : gv;
    const float* bb = (mat == 0) ? bq : (mat == 1) ? bk : bv;
    u8* Sp = (mat == 0) ? Qs : (mat == 1) ? Ks : Vs;
    __shared__ double red[12];
    int d = threadIdx.x;
    int wv_ = d >> 6, lane = d & 63;
    float gd = g[d], bd = bb[d];
    float v = 0.f;
    for (int t = 0; t < T_; ++t) {
        // exact y: sequential f32 adds over set bits, ascending k (== np sgemm)
        float y = 0.f;
        for (int kw = 0; kw < 12; ++kw) {
            u64 m = Am[((size_t)t * 12 + kw) * BS_ + bs];
            while (m) {
                int kb = __builtin_ctzll(m);
                m &= m - 1;
                y += W[(size_t)(kw * 64 + kb) * D_ + d];
            }
        }
        // f64 LN over the 768 threads
        double s = (double)y;
        #pragma unroll
        for (int o = 1; o < 64; o <<= 1) s += __shfl_xor(s, o, 64);
        if (lane == 0) red[wv_] = s;
        __syncthreads();
        double stot = 0.0;
        #pragma unroll
        for (int i = 0; i < 12; ++i) stot += red[i];
        __syncthreads();
        float mean = (float)(stot / 768.0);
        float dd = y - mean;
        float sq = dd * dd;
        double q = (double)sq;
        #pragma unroll
        for (int o = 1; o < 64; o <<= 1) q += __shfl_xor(q, o, 64);
        if (lane == 0) red[wv_] = q;
        __syncthreads();
        double qtot = 0.0;
        #pragma unroll
        for (int i = 0; i < 12; ++i) qtot += red[i];
        __syncthreads();
        float var = (float)(qtot / 768.0);
        float inv = 1.0f / __fsqrt_rn(var + LN_EPS);
        float yn = ((dd * inv) * gd) + bd;
        v += yn;
        bool sp = (v >= 1.0f);
        Sp[((size_t)t * BS_ + bs) * D_ + d] = sp ? (u8)1 : (u8)0;
        if (sp) v = 0.f;
    }
}

// ---- QK column-dot over S (exact integer counts) ----
__global__ void k_qkred(const u8* __restrict__ Q, const u8* __restrict__ K,
                        float* __restrict__ QK) {
    int bid = blockIdx.x;           // 256 blocks, 192 threads
    int sg = bid & 7, tb = bid >> 3;
    int tid = threadIdx.x;
    int c4 = tid * 4;
    size_t base = (size_t)tb * S_ * D_ + (size_t)sg * 128 * D_;
    int acc[4] = {0, 0, 0, 0};
    for (int s = 0; s < 128; ++s) {
        uchar4 q = *(const uchar4*)(Q + base + (size_t)s * D_ + c4);
        uchar4 k = *(const uchar4*)(K + base + (size_t)s * D_ + c4);
        acc[0] += q.x & k.x; acc[1] += q.y & k.y; acc[2] += q.z & k.z; acc[3] += q.w & k.w;
    }
    float* dst = QK + (size_t)tb * D_ + c4;
    #pragma unroll
    for (int j = 0; j < 4; ++j) atomicAdd(dst + j, (float)acc[j]);
}

// ---- IF over T on QK counts (integer-exact) ----
__global__ void k_qkif(const float* __restrict__ QK, u8* __restrict__ QKs) {
    int i = blockIdx.x * 256 + threadIdx.x;     // 24 blocks
    float v = 0.f;
    for (int t = 0; t < T_; ++t) {
        v += QK[t * (B_ * D_) + i];
        bool s = (v >= 1.0f);
        QKs[t * (B_ * D_) + i] = s ? 1 : 0;
        if (s) v = 0.f;
    }
}

// ---- QKV = V * QKs -> bf16 {0,1} ----
__global__ void k_qkv(const u8* __restrict__ V, const u8* __restrict__ QKs,
                      u16* __restrict__ O) {
    size_t e = ((size_t)blockIdx.x * 256 + threadIdx.x) * 4;    // 24576 blocks
    uchar4 v = *(const uchar4*)(V + e);
    size_t d = e % D_;
    size_t b = (e / ((size_t)S_ * D_)) % B_;
    size_t t = e / BSD_;
    uchar4 qk = *(const uchar4*)(QKs + t * (B_ * D_) + b * D_ + d);
    ushort4 o;
    o.x = (v.x & qk.x) ? 0x3F80 : 0;
    o.y = (v.y & qk.y) ? 0x3F80 : 0;
    o.z = (v.z & qk.z) ? 0x3F80 : 0;
    o.w = (v.w & qk.w) ? 0x3F80 : 0;
    *(ushort4*)(O + e) = o;
}

// ---- block reduction helper (final LN only; tolerance loose) ----
__device__ __forceinline__ float block_sum(float v, float* red) {
    #pragma unroll
    for (int o = 32; o > 0; o >>= 1) v += __shfl_down(v, o, 64);
    int lane = threadIdx.x & 63, w = threadIdx.x >> 6;
    __syncthreads();
    if (lane == 0) red[w] = v;
    __syncthreads();
    return (red[0] + red[1]) + (red[2] + red[3]);
}

__global__ __launch_bounds__(256)
void k_lnfinal(const float* __restrict__ Y, const float* __restrict__ g,
               const float* __restrict__ bt, float* __restrict__ out) {
    #pragma clang fp contract(off)
    __shared__ float red[4];
    size_t row = (size_t)blockIdx.x * D_;       // 32768 rows
    int tid = threadIdx.x;
    float y[3];
    float s = 0.f;
    #pragma unroll
    for (int j = 0; j < 3; ++j) { y[j] = Y[row + tid + j * 256]; s += y[j]; }
    float mean = block_sum(s, red) / 768.0f;
    float q = 0.f;
    #pragma unroll
    for (int j = 0; j < 3; ++j) { float d = y[j] - mean; q += d * d; }
    float var = block_sum(q, red) / 768.0f;
    float inv = 1.0f / __fsqrt_rn(var + LN_EPS);
    #pragma unroll
    for (int j = 0; j < 3; ++j) {
        int c = tid + j * 256;
        out[row + c] = (y[j] - mean) * inv * g[c] + bt[c];
    }
}

extern "C" void kernel_launch(void* const* d_in, const int* in_sizes, int n_in,
                              void* d_out, int out_size, void* d_ws, size_t ws_size,
                              hipStream_t stream) {
    const float* x  = (const float*)d_in[0];
    const float* wq = (const float*)d_in[1];
    const float* wk = (const float*)d_in[2];
    const float* wv = (const float*)d_in[3];
    const float* wo = (const float*)d_in[4];
    const float* gq = (const float*)d_in[5];
    const float* bq = (const float*)d_in[6];
    const float* gk = (const float*)d_in[7];
    const float* bk = (const float*)d_in[8];
    const float* gv = (const float*)d_in[9];
    const float* bv = (const float*)d_in[10];
    const float* go = (const float*)d_in[11];
    const float* bo = (const float*)d_in[12];
    float* out = (float*)d_out;

    char* ws = (char*)d_ws;
    size_t off = 0;
    auto alloc = [&](size_t bytes) -> void* {
        void* p = ws + off;
        off += (bytes + 255) & ~(size_t)255;
        return p;
    };
    u64* Am    = (u64*)alloc((size_t)T_ * 12 * BS_ * 8);     // 3 MB bitmasks
    u16* Ab    = (u16*)alloc((size_t)M_ * D_ * 2);           // 48 MB bf16 spikes / reused for QKV
    float* Y   = (float*)alloc((size_t)M_ * D_ * 4);         // 96 MB GEMM out
    u8* Qs     = (u8*)alloc((size_t)M_ * D_);
    u8* Ks     = (u8*)alloc((size_t)M_ * D_);
    u8* Vs     = (u8*)alloc((size_t)M_ * D_);
    u16* Whi   = (u16*)alloc((size_t)3 * D_ * D_ * 2);
    u16* Wlo   = (u16*)alloc((size_t)3 * D_ * D_ * 2);
    u16* Wo    = (u16*)alloc((size_t)D_ * D_ * 2);
    float* QK  = (float*)alloc((size_t)T_ * B_ * D_ * 4);
    u8* QKs    = (u8*)alloc((size_t)T_ * B_ * D_);
    u8* flags  = (u8*)alloc((size_t)3 * BS_);

    hipMemsetAsync(QK, 0, (size_t)T_ * B_ * D_ * 4, stream);
    hipMemsetAsync(flags, 0, (size_t)3 * BS_, stream);

    // 1. IF over x -> bitmasks + bf16 spikes (bit-exact)
    k_if_mask<<<BS_, 768, 0, stream>>>(x, Am, Ab);
    // 2. weight conversion
    k_wconv<<<(4 * D_ * D_) / 256, 256, 0, stream>>>(wq, wk, wv, wo, Whi, Wlo, Wo);
    // 3. Q/K/V: split-bf16 MFMA GEMM + f64-LN + IF + boundary flags
    const int ntn = D_ / 128;                           // 6
    const int gemm_grid = (M_ / 128) * ntn;             // 1536
    k_gemm<2><<<gemm_grid, 256, 0, stream>>>(Ab, Whi + 0 * D_ * D_, Wlo + 0 * D_ * D_, Y, ntn, D_);
    k_lnif<<<BS_ / 4, 256, 0, stream>>>(Y, gq, bq, Qs, flags + 0 * BS_);
    k_gemm<2><<<gemm_grid, 256, 0, stream>>>(Ab, Whi + 1 * D_ * D_, Wlo + 1 * D_ * D_, Y, ntn, D_);
    k_lnif<<<BS_ / 4, 256, 0, stream>>>(Y, gk, bk, Ks, flags + 1 * BS_);
    k_gemm<2><<<gemm_grid, 256, 0, stream>>>(Ab, Whi + 2 * D_ * D_, Wlo + 2 * D_ * D_, Y, ntn, D_);
    k_lnif<<<BS_ / 4, 256, 0, stream>>>(Y, gv, bv, Vs, flags + 2 * BS_);
    // 3b. exact repair of boundary-flagged rows (reproduces np arithmetic)
    k_repair<<<dim3(BS_, 3), 768, 0, stream>>>(Am, wq, wk, wv, gq, bq, gk, bk, gv, bv,
                                               Qs, Ks, Vs, flags);
    // 4. QK column-dot + IF (integer-exact)
    k_qkred<<<T_ * B_ * 8, 192, 0, stream>>>(Qs, Ks, QK);
    k_qkif<<<(B_ * D_) / 256, 256, 0, stream>>>(QK, QKs);
    // 5. QKV = V * QKs -> bf16 (reuse Ab)
    k_qkv<<<(M_ * D_) / 4 / 256, 256, 0, stream>>>(Vs, QKs, Ab);
    // 6. output projection (bf16 MFMA; loose tolerance) + final LN
    k_gemm<1><<<gemm_grid, 256, 0, stream>>>(Ab, Wo, Wo, Y, ntn, D_);
    k_lnfinal<<<M_, 256, 0, stream>>>(Y, go, bo, out);
}

// Round 4
// 788.214 us; speedup vs baseline: 3.9616x; 3.9616x over previous
//
#include <hip/hip_runtime.h>
#include <hip/hip_bf16.h>

#define T_ 4
#define B_ 8
#define S_ 1024
#define D_ 768
#define BS_ (B_*S_)            // 8192
#define M_ (T_*B_*S_)          // 32768
#define BSD_ (B_*S_*D_)        // 6291456
#define LN_EPS 1e-5f
#define TAU 4e-5f

typedef unsigned short u16;
typedef unsigned char u8;
typedef unsigned long long u64;
typedef __bf16 bf16x8 __attribute__((ext_vector_type(8)));
typedef float f32x4 __attribute__((ext_vector_type(4)));

// ---- IF over x -> bitmask spikes + bf16 spikes, bit-exact vs np ----
__global__ __launch_bounds__(768)
void k_if_mask(const float* __restrict__ x, u64* __restrict__ Am, u16* __restrict__ Ab) {
    int bs = blockIdx.x;           // 8192 blocks
    int d = threadIdx.x;           // 768 threads
    int wv = d >> 6, lane = d & 63;
    float v = 0.f;
    for (int t = 0; t < T_; ++t) {
        v += x[(size_t)t * BSD_ + (size_t)bs * D_ + d];
        bool s = (v >= 1.0f);
        u64 m = __ballot(s);
        if (lane == 0) Am[((size_t)t * 12 + wv) * BS_ + bs] = m;
        Ab[(size_t)t * BSD_ + (size_t)bs * D_ + d] = s ? 0x3F80 : 0;
        if (s) v = 0.f;
    }
}

// ---- weight convert: Bt layout [N][K], hi/lo split for q/k/v; bf16 for wo ----
__global__ void k_wconv(const float* __restrict__ wq, const float* __restrict__ wk,
                        const float* __restrict__ wv, const float* __restrict__ wo,
                        u16* __restrict__ Whi, u16* __restrict__ Wlo, u16* __restrict__ Wo) {
    int idx = blockIdx.x * 256 + threadIdx.x;       // 9216 blocks
    int mat = idx / (D_ * D_);
    int r = idx % (D_ * D_);
    int n = r / D_;
    int k = r % D_;
    const float* src = (mat == 0) ? wq : (mat == 1) ? wk : (mat == 2) ? wv : wo;
    float w = src[k * D_ + n];
    __bf16 hi = (__bf16)w;
    u16 uhi = __builtin_bit_cast(u16, hi);
    if (mat == 3) { Wo[r] = uhi; return; }
    float lo = w - (float)hi;
    u16 ulo = __builtin_bit_cast(u16, (__bf16)lo);
    Whi[(size_t)mat * D_ * D_ + r] = uhi;
    Wlo[(size_t)mat * D_ * D_ + r] = ulo;
}

// ---- MFMA GEMM: C[M,N] = A[M,K] @ Bt[N,K]^T (accumulate over NMATS B's) ----
__device__ __forceinline__ void gload16(const void* g, void* l) {
    __builtin_amdgcn_global_load_lds(
        (const __attribute__((address_space(1))) unsigned int*)g,
        (__attribute__((address_space(3))) unsigned int*)l, 16, 0, 0);
}

template<int NMATS>
__global__ __launch_bounds__(256)
void k_gemm(const u16* __restrict__ A, const u16* __restrict__ B0,
            const u16* __restrict__ B1, float* __restrict__ C, int ntn, int N) {
    __shared__ __align__(16) u16 As[128 * 32];
    __shared__ __align__(16) u16 Bs[128 * 32];
    int bid = blockIdx.x;
    int bn = bid % ntn, bm = bid / ntn;
    int tid = threadIdx.x;
    int l = tid & 63, w = tid >> 6;
    int wr = w >> 1, wc = w & 1;
    int lan16 = l & 15, kh = l >> 4;

    f32x4 acc[4][4];
    #pragma unroll
    for (int m = 0; m < 4; ++m)
        #pragma unroll
        for (int n = 0; n < 4; ++n)
            #pragma unroll
            for (int r = 0; r < 4; ++r) acc[m][n][r] = 0.f;

    int arow = bm * 128 + (tid >> 2);
    int brow = bn * 128 + (tid >> 2);
    int colb = (tid & 3) * 8;
    char* ldsA = (char*)As + ((tid >> 6) << 10);
    char* ldsB = (char*)Bs + ((tid >> 6) << 10);

    for (int mat = 0; mat < NMATS; ++mat) {
        const u16* Bt = (mat == 0) ? B0 : B1;
        for (int kk = 0; kk < 768; kk += 32) {
            gload16(A  + (size_t)(arow     ) * 768 + kk + colb, ldsA);
            gload16(A  + (size_t)(arow + 64) * 768 + kk + colb, ldsA + 4096);
            gload16(Bt + (size_t)(brow     ) * 768 + kk + colb, ldsB);
            gload16(Bt + (size_t)(brow + 64) * 768 + kk + colb, ldsB + 4096);
            __syncthreads();
            bf16x8 af[4], bf[4];
            #pragma unroll
            for (int m = 0; m < 4; ++m)
                af[m] = *(const bf16x8*)((const char*)As + (wr * 64 + m * 16 + lan16) * 64 + kh * 16);
            #pragma unroll
            for (int n = 0; n < 4; ++n)
                bf[n] = *(const bf16x8*)((const char*)Bs + (wc * 64 + n * 16 + lan16) * 64 + kh * 16);
            #pragma unroll
            for (int m = 0; m < 4; ++m)
                #pragma unroll
                for (int n = 0; n < 4; ++n)
                    acc[m][n] = __builtin_amdgcn_mfma_f32_16x16x32_bf16(af[m], bf[n], acc[m][n], 0, 0, 0);
            __syncthreads();
        }
    }
    #pragma unroll
    for (int m = 0; m < 4; ++m)
        #pragma unroll
        for (int n = 0; n < 4; ++n)
            #pragma unroll
            for (int r = 0; r < 4; ++r) {
                int crow = bm * 128 + wr * 64 + m * 16 + kh * 4 + r;
                int ccol = bn * 128 + wc * 64 + n * 16 + lan16;
                C[(size_t)crow * N + ccol] = acc[m][n][r];
            }
}

// ---- LN (f64 mean/var) + IF -> u8 spikes, with boundary-margin flagging ----
__global__ __launch_bounds__(256)
void k_lnif(const float* __restrict__ Y, const float* __restrict__ g,
            const float* __restrict__ bt, u8* __restrict__ Sp, u8* __restrict__ flag) {
    #pragma clang fp contract(off)
    int row = blockIdx.x * 4 + (threadIdx.x >> 6);   // (b,s) 0..8191
    int lane = threadIdx.x & 63;
    float v[12];
    #pragma unroll
    for (int i = 0; i < 12; ++i) v[i] = 0.f;
    float gv[12], bv[12];
    #pragma unroll
    for (int i = 0; i < 12; ++i) { gv[i] = g[lane + 64*i]; bv[i] = bt[lane + 64*i]; }
    bool fl = false;
    for (int t = 0; t < T_; ++t) {
        size_t base = ((size_t)t * BS_ + row) * D_;
        float xv[12];
        double s = 0.0;
        #pragma unroll
        for (int i = 0; i < 12; ++i) { xv[i] = Y[base + lane + 64*i]; s += (double)xv[i]; }
        #pragma unroll
        for (int o = 1; o < 64; o <<= 1) s += __shfl_xor(s, o, 64);
        s = __shfl(s, 0, 64);
        float m = (float)(s / 768.0);
        float d[12];
        double q = 0.0;
        #pragma unroll
        for (int i = 0; i < 12; ++i) { d[i] = xv[i] - m; float sq = d[i]*d[i]; q += (double)sq; }
        #pragma unroll
        for (int o = 1; o < 64; o <<= 1) q += __shfl_xor(q, o, 64);
        q = __shfl(q, 0, 64);
        float var = (float)(q / 768.0);
        float inv = 1.0f / __fsqrt_rn(var + LN_EPS);
        #pragma unroll
        for (int i = 0; i < 12; ++i) {
            float yn = ((d[i] * inv) * gv[i]) + bv[i];
            v[i] += yn;
            fl = fl || (fabsf(v[i] - 1.0f) < TAU);
            bool sp = (v[i] >= 1.0f);
            Sp[base + lane + 64*i] = sp ? (u8)1 : (u8)0;
            if (sp) v[i] = 0.f;
        }
    }
    u64 bal = __ballot(fl);
    if (lane == 0 && bal != 0ull) flag[row] = 1;
}

// ---- repair flagged rows: exact bit-sequential GEMM (latency-hidden) + f64 LN ----
__global__ __launch_bounds__(768)
void k_repair(const u64* __restrict__ Am,
              const float* __restrict__ wq, const float* __restrict__ wk,
              const float* __restrict__ wv,
              const float* __restrict__ gq, const float* __restrict__ bq,
              const float* __restrict__ gk, const float* __restrict__ bk,
              const float* __restrict__ gv, const float* __restrict__ bv,
              u8* __restrict__ Qs, u8* __restrict__ Ks, u8* __restrict__ Vs,
              const u8* __restrict__ flags) {
    #pragma clang fp contract(off)
    int mat = blockIdx.y;
    int bs = blockIdx.x;
    if (!flags[(size_t)mat * BS_ + bs]) return;
    const float* W = (mat == 0) ? wq : (mat == 1) ? wk : wv;
    const float* g = (mat == 0) ? gq : (mat == 1) ? gk : gv;
    const float* bb = (mat == 0) ? bq : (mat == 1) ? bk : bv;
    u8* Sp = (mat == 0) ? Qs : (mat == 1) ? Ks : Vs;
    __shared__ double red[12];
    __shared__ u64 mword_s[12];
    __shared__ int pops_s[12];
    __shared__ int cnt_s;
    __shared__ u16 idxs[768];
    int d = threadIdx.x;
    int wv_ = d >> 6, lane = d & 63;
    float gd = g[d], bd = bb[d];
    float v = 0.f;
    for (int t = 0; t < T_; ++t) {
        // build ascending set-bit index list in LDS (np's k order)
        if (d < 12) {
            u64 m = Am[((size_t)t * 12 + d) * BS_ + bs];
            mword_s[d] = m;
            pops_s[d] = __popcll(m);
        }
        __syncthreads();
        if (d < 12) {
            int off = 0;
            for (int j = 0; j < d; ++j) off += pops_s[j];
            u64 m = mword_s[d];
            int base = d * 64;
            while (m) {
                int kb = __builtin_ctzll(m);
                m &= m - 1;
                idxs[off++] = (u16)(base + kb);
            }
            if (d == 11) cnt_s = off;
        }
        __syncthreads();
        int cnt = cnt_s;
        // exact y: sequential f32 adds, ascending k; 4-wide load batching for ILP
        float y = 0.f;
        int i = 0;
        for (; i + 4 <= cnt; i += 4) {
            float w0 = W[(size_t)idxs[i    ] * D_ + d];
            float w1 = W[(size_t)idxs[i + 1] * D_ + d];
            float w2 = W[(size_t)idxs[i + 2] * D_ + d];
            float w3 = W[(size_t)idxs[i + 3] * D_ + d];
            y += w0; y += w1; y += w2; y += w3;
        }
        for (; i < cnt; ++i) y += W[(size_t)idxs[i] * D_ + d];
        // f64 LN over the 768 threads
        double s = (double)y;
        #pragma unroll
        for (int o = 1; o < 64; o <<= 1) s += __shfl_xor(s, o, 64);
        if (lane == 0) red[wv_] = s;
        __syncthreads();
        double stot = 0.0;
        #pragma unroll
        for (int j = 0; j < 12; ++j) stot += red[j];
        __syncthreads();
        float mean = (float)(stot / 768.0);
        float dd = y - mean;
        float sq = dd * dd;
        double q = (double)sq;
        #pragma unroll
        for (int o = 1; o < 64; o <<= 1) q += __shfl_xor(q, o, 64);
        if (lane == 0) red[wv_] = q;
        __syncthreads();
        double qtot = 0.0;
        #pragma unroll
        for (int j = 0; j < 12; ++j) qtot += red[j];
        __syncthreads();
        float var = (float)(qtot / 768.0);
        float inv = 1.0f / __fsqrt_rn(var + LN_EPS);
        float yn = ((dd * inv) * gd) + bd;
        v += yn;
        bool sp = (v >= 1.0f);
        Sp[((size_t)t * BS_ + bs) * D_ + d] = sp ? (u8)1 : (u8)0;
        if (sp) v = 0.f;
    }
}

// ---- QK column-dot over S (exact integer counts) ----
__global__ void k_qkred(const u8* __restrict__ Q, const u8* __restrict__ K,
                        float* __restrict__ QK) {
    int bid = blockIdx.x;           // 256 blocks, 192 threads
    int sg = bid & 7, tb = bid >> 3;
    int tid = threadIdx.x;
    int c4 = tid * 4;
    size_t base = (size_t)tb * S_ * D_ + (size_t)sg * 128 * D_;
    int acc[4] = {0, 0, 0, 0};
    for (int s = 0; s < 128; ++s) {
        uchar4 q = *(const uchar4*)(Q + base + (size_t)s * D_ + c4);
        uchar4 k = *(const uchar4*)(K + base + (size_t)s * D_ + c4);
        acc[0] += q.x & k.x; acc[1] += q.y & k.y; acc[2] += q.z & k.z; acc[3] += q.w & k.w;
    }
    float* dst = QK + (size_t)tb * D_ + c4;
    #pragma unroll
    for (int j = 0; j < 4; ++j) atomicAdd(dst + j, (float)acc[j]);
}

// ---- IF over T on QK counts (integer-exact) ----
__global__ void k_qkif(const float* __restrict__ QK, u8* __restrict__ QKs) {
    int i = blockIdx.x * 256 + threadIdx.x;     // 24 blocks
    float v = 0.f;
    for (int t = 0; t < T_; ++t) {
        v += QK[t * (B_ * D_) + i];
        bool s = (v >= 1.0f);
        QKs[t * (B_ * D_) + i] = s ? 1 : 0;
        if (s) v = 0.f;
    }
}

// ---- QKV = V * QKs -> bf16 {0,1} ----
__global__ void k_qkv(const u8* __restrict__ V, const u8* __restrict__ QKs,
                      u16* __restrict__ O) {
    size_t e = ((size_t)blockIdx.x * 256 + threadIdx.x) * 4;    // 24576 blocks
    uchar4 v = *(const uchar4*)(V + e);
    size_t d = e % D_;
    size_t b = (e / ((size_t)S_ * D_)) % B_;
    size_t t = e / BSD_;
    uchar4 qk = *(const uchar4*)(QKs + t * (B_ * D_) + b * D_ + d);
    ushort4 o;
    o.x = (v.x & qk.x) ? 0x3F80 : 0;
    o.y = (v.y & qk.y) ? 0x3F80 : 0;
    o.z = (v.z & qk.z) ? 0x3F80 : 0;
    o.w = (v.w & qk.w) ? 0x3F80 : 0;
    *(ushort4*)(O + e) = o;
}

// ---- block reduction helper (final LN only; tolerance loose) ----
__device__ __forceinline__ float block_sum(float v, float* red) {
    #pragma unroll
    for (int o = 32; o > 0; o >>= 1) v += __shfl_down(v, o, 64);
    int lane = threadIdx.x & 63, w = threadIdx.x >> 6;
    __syncthreads();
    if (lane == 0) red[w] = v;
    __syncthreads();
    return (red[0] + red[1]) + (red[2] + red[3]);
}

__global__ __launch_bounds__(256)
void k_lnfinal(const float* __restrict__ Y, const float* __restrict__ g,
               const float* __restrict__ bt, float* __restrict__ out) {
    #pragma clang fp contract(off)
    __shared__ float red[4];
    size_t row = (size_t)blockIdx.x * D_;       // 32768 rows
    int tid = threadIdx.x;
    float y[3];
    float s = 0.f;
    #pragma unroll
    for (int j = 0; j < 3; ++j) { y[j] = Y[row + tid + j * 256]; s += y[j]; }
    float mean = block_sum(s, red) / 768.0f;
    float q = 0.f;
    #pragma unroll
    for (int j = 0; j < 3; ++j) { float d = y[j] - mean; q += d * d; }
    float var = block_sum(q, red) / 768.0f;
    float inv = 1.0f / __fsqrt_rn(var + LN_EPS);
    #pragma unroll
    for (int j = 0; j < 3; ++j) {
        int c = tid + j * 256;
        out[row + c] = (y[j] - mean) * inv * g[c] + bt[c];
    }
}

extern "C" void kernel_launch(void* const* d_in, const int* in_sizes, int n_in,
                              void* d_out, int out_size, void* d_ws, size_t ws_size,
                              hipStream_t stream) {
    const float* x  = (const float*)d_in[0];
    const float* wq = (const float*)d_in[1];
    const float* wk = (const float*)d_in[2];
    const float* wv = (const float*)d_in[3];
    const float* wo = (const float*)d_in[4];
    const float* gq = (const float*)d_in[5];
    const float* bq = (const float*)d_in[6];
    const float* gk = (const float*)d_in[7];
    const float* bk = (const float*)d_in[8];
    const float* gv = (const float*)d_in[9];
    const float* bv = (const float*)d_in[10];
    const float* go = (const float*)d_in[11];
    const float* bo = (const float*)d_in[12];
    float* out = (float*)d_out;

    char* ws = (char*)d_ws;
    size_t off = 0;
    auto alloc = [&](size_t bytes) -> void* {
        void* p = ws + off;
        off += (bytes + 255) & ~(size_t)255;
        return p;
    };
    u64* Am    = (u64*)alloc((size_t)T_ * 12 * BS_ * 8);     // 3 MB bitmasks
    u16* Ab    = (u16*)alloc((size_t)M_ * D_ * 2);           // 48 MB bf16 spikes / reused for QKV
    float* Y   = (float*)alloc((size_t)M_ * D_ * 4);         // 96 MB GEMM out
    u8* Qs     = (u8*)alloc((size_t)M_ * D_);
    u8* Ks     = (u8*)alloc((size_t)M_ * D_);
    u8* Vs     = (u8*)alloc((size_t)M_ * D_);
    u16* Whi   = (u16*)alloc((size_t)3 * D_ * D_ * 2);
    u16* Wlo   = (u16*)alloc((size_t)3 * D_ * D_ * 2);
    u16* Wo    = (u16*)alloc((size_t)D_ * D_ * 2);
    float* QK  = (float*)alloc((size_t)T_ * B_ * D_ * 4);
    u8* QKs    = (u8*)alloc((size_t)T_ * B_ * D_);
    u8* flags  = (u8*)alloc((size_t)3 * BS_);

    hipMemsetAsync(QK, 0, (size_t)T_ * B_ * D_ * 4, stream);
    hipMemsetAsync(flags, 0, (size_t)3 * BS_, stream);

    // 1. IF over x -> bitmasks + bf16 spikes (bit-exact)
    k_if_mask<<<BS_, 768, 0, stream>>>(x, Am, Ab);
    // 2. weight conversion
    k_wconv<<<(4 * D_ * D_) / 256, 256, 0, stream>>>(wq, wk, wv, wo, Whi, Wlo, Wo);
    // 3. Q/K/V: split-bf16 MFMA GEMM + f64-LN + IF + boundary flags
    const int ntn = D_ / 128;                           // 6
    const int gemm_grid = (M_ / 128) * ntn;             // 1536
    k_gemm<2><<<gemm_grid, 256, 0, stream>>>(Ab, Whi + 0 * D_ * D_, Wlo + 0 * D_ * D_, Y, ntn, D_);
    k_lnif<<<BS_ / 4, 256, 0, stream>>>(Y, gq, bq, Qs, flags + 0 * BS_);
    k_gemm<2><<<gemm_grid, 256, 0, stream>>>(Ab, Whi + 1 * D_ * D_, Wlo + 1 * D_ * D_, Y, ntn, D_);
    k_lnif<<<BS_ / 4, 256, 0, stream>>>(Y, gk, bk, Ks, flags + 1 * BS_);
    k_gemm<2><<<gemm_grid, 256, 0, stream>>>(Ab, Whi + 2 * D_ * D_, Wlo + 2 * D_ * D_, Y, ntn, D_);
    k_lnif<<<BS_ / 4, 256, 0, stream>>>(Y, gv, bv, Vs, flags + 2 * BS_);
    // 3b. exact repair of boundary-flagged rows (reproduces np arithmetic)
    k_repair<<<dim3(BS_, 3), 768, 0, stream>>>(Am, wq, wk, wv, gq, bq, gk, bk, gv, bv,
                                               Qs, Ks, Vs, flags);
    // 4. QK column-dot + IF (integer-exact)
    k_qkred<<<T_ * B_ * 8, 192, 0, stream>>>(Qs, Ks, QK);
    k_qkif<<<(B_ * D_) / 256, 256, 0, stream>>>(QK, QKs);
    // 5. QKV = V * QKs -> bf16 (reuse Ab)
    k_qkv<<<(M_ * D_) / 4 / 256, 256, 0, stream>>>(Vs, QKs, Ab);
    // 6. output projection (bf16 MFMA; loose tolerance) + final LN
    k_gemm<1><<<gemm_grid, 256, 0, stream>>>(Ab, Wo, Wo, Y, ntn, D_);
    k_lnfinal<<<M_, 256, 0, stream>>>(Y, go, bo, out);
}

// Round 5
// 786.024 us; speedup vs baseline: 3.9726x; 1.0028x over previous
//
#include <hip/hip_runtime.h>
#include <hip/hip_bf16.h>

#define T_ 4
#define B_ 8
#define S_ 1024
#define D_ 768
#define BS_ (B_*S_)            // 8192
#define M_ (T_*B_*S_)          // 32768
#define BSD_ (B_*S_*D_)        // 6291456
#define LN_EPS 1e-5f
#define TAU 4e-5f

typedef unsigned short u16;
typedef unsigned char u8;
typedef unsigned long long u64;
typedef __bf16 bf16x8 __attribute__((ext_vector_type(8)));
typedef float f32x4 __attribute__((ext_vector_type(4)));

// ---- IF over x -> bitmask spikes + bf16 spikes, bit-exact vs np ----
__global__ __launch_bounds__(768)
void k_if_mask(const float* __restrict__ x, u64* __restrict__ Am, u16* __restrict__ Ab) {
    int bs = blockIdx.x;           // 8192 blocks
    int d = threadIdx.x;           // 768 threads
    int wv = d >> 6, lane = d & 63;
    float v = 0.f;
    for (int t = 0; t < T_; ++t) {
        v += x[(size_t)t * BSD_ + (size_t)bs * D_ + d];
        bool s = (v >= 1.0f);
        u64 m = __ballot(s);
        if (lane == 0) Am[((size_t)t * 12 + wv) * BS_ + bs] = m;
        Ab[(size_t)t * BSD_ + (size_t)bs * D_ + d] = s ? 0x3F80 : 0;
        if (s) v = 0.f;
    }
}

// ---- weight convert: Bt layout [N][K], hi/lo split for q/k/v; bf16 for wo ----
__global__ void k_wconv(const float* __restrict__ wq, const float* __restrict__ wk,
                        const float* __restrict__ wv, const float* __restrict__ wo,
                        u16* __restrict__ Whi, u16* __restrict__ Wlo, u16* __restrict__ Wo) {
    int idx = blockIdx.x * 256 + threadIdx.x;       // 9216 blocks
    int mat = idx / (D_ * D_);
    int r = idx % (D_ * D_);
    int n = r / D_;
    int k = r % D_;
    const float* src = (mat == 0) ? wq : (mat == 1) ? wk : (mat == 2) ? wv : wo;
    float w = src[k * D_ + n];
    __bf16 hi = (__bf16)w;
    u16 uhi = __builtin_bit_cast(u16, hi);
    if (mat == 3) { Wo[r] = uhi; return; }
    float lo = w - (float)hi;
    u16 ulo = __builtin_bit_cast(u16, (__bf16)lo);
    Whi[(size_t)mat * D_ * D_ + r] = uhi;
    Wlo[(size_t)mat * D_ * D_ + r] = ulo;
}

// ---- MFMA GEMM: C[M,N] = A[M,K] @ Bt[N,K]^T (accumulate over NMATS B's) ----
__device__ __forceinline__ void gload16(const void* g, void* l) {
    __builtin_amdgcn_global_load_lds(
        (const __attribute__((address_space(1))) unsigned int*)g,
        (__attribute__((address_space(3))) unsigned int*)l, 16, 0, 0);
}

template<int NMATS>
__global__ __launch_bounds__(256)
void k_gemm(const u16* __restrict__ A, const u16* __restrict__ B0,
            const u16* __restrict__ B1, float* __restrict__ C, int ntn, int N) {
    __shared__ __align__(16) u16 As[128 * 32];
    __shared__ __align__(16) u16 Bs[128 * 32];
    int bid = blockIdx.x;
    int bn = bid % ntn, bm = bid / ntn;
    int tid = threadIdx.x;
    int l = tid & 63, w = tid >> 6;
    int wr = w >> 1, wc = w & 1;
    int lan16 = l & 15, kh = l >> 4;

    f32x4 acc[4][4];
    #pragma unroll
    for (int m = 0; m < 4; ++m)
        #pragma unroll
        for (int n = 0; n < 4; ++n)
            #pragma unroll
            for (int r = 0; r < 4; ++r) acc[m][n][r] = 0.f;

    int arow = bm * 128 + (tid >> 2);
    int brow = bn * 128 + (tid >> 2);
    int colb = (tid & 3) * 8;
    char* ldsA = (char*)As + ((tid >> 6) << 10);
    char* ldsB = (char*)Bs + ((tid >> 6) << 10);

    for (int mat = 0; mat < NMATS; ++mat) {
        const u16* Bt = (mat == 0) ? B0 : B1;
        for (int kk = 0; kk < 768; kk += 32) {
            gload16(A  + (size_t)(arow     ) * 768 + kk + colb, ldsA);
            gload16(A  + (size_t)(arow + 64) * 768 + kk + colb, ldsA + 4096);
            gload16(Bt + (size_t)(brow     ) * 768 + kk + colb, ldsB);
            gload16(Bt + (size_t)(brow + 64) * 768 + kk + colb, ldsB + 4096);
            __syncthreads();
            bf16x8 af[4], bf[4];
            #pragma unroll
            for (int m = 0; m < 4; ++m)
                af[m] = *(const bf16x8*)((const char*)As + (wr * 64 + m * 16 + lan16) * 64 + kh * 16);
            #pragma unroll
            for (int n = 0; n < 4; ++n)
                bf[n] = *(const bf16x8*)((const char*)Bs + (wc * 64 + n * 16 + lan16) * 64 + kh * 16);
            #pragma unroll
            for (int m = 0; m < 4; ++m)
                #pragma unroll
                for (int n = 0; n < 4; ++n)
                    acc[m][n] = __builtin_amdgcn_mfma_f32_16x16x32_bf16(af[m], bf[n], acc[m][n], 0, 0, 0);
            __syncthreads();
        }
    }
    #pragma unroll
    for (int m = 0; m < 4; ++m)
        #pragma unroll
        for (int n = 0; n < 4; ++n)
            #pragma unroll
            for (int r = 0; r < 4; ++r) {
                int crow = bm * 128 + wr * 64 + m * 16 + kh * 4 + r;
                int ccol = bn * 128 + wc * 64 + n * 16 + lan16;
                C[(size_t)crow * N + ccol] = acc[m][n][r];
            }
}

// ---- LN (f64 mean/var) + IF -> u8 spikes, with boundary-margin flagging ----
__global__ __launch_bounds__(256)
void k_lnif(const float* __restrict__ Y, const float* __restrict__ g,
            const float* __restrict__ bt, u8* __restrict__ Sp, u8* __restrict__ flag) {
    #pragma clang fp contract(off)
    int row = blockIdx.x * 4 + (threadIdx.x >> 6);   // (b,s) 0..8191
    int lane = threadIdx.x & 63;
    float v[12];
    #pragma unroll
    for (int i = 0; i < 12; ++i) v[i] = 0.f;
    float gv[12], bv[12];
    #pragma unroll
    for (int i = 0; i < 12; ++i) { gv[i] = g[lane + 64*i]; bv[i] = bt[lane + 64*i]; }
    bool fl = false;
    for (int t = 0; t < T_; ++t) {
        size_t base = ((size_t)t * BS_ + row) * D_;
        float xv[12];
        double s = 0.0;
        #pragma unroll
        for (int i = 0; i < 12; ++i) { xv[i] = Y[base + lane + 64*i]; s += (double)xv[i]; }
        #pragma unroll
        for (int o = 1; o < 64; o <<= 1) s += __shfl_xor(s, o, 64);
        s = __shfl(s, 0, 64);
        float m = (float)(s / 768.0);
        float d[12];
        double q = 0.0;
        #pragma unroll
        for (int i = 0; i < 12; ++i) { d[i] = xv[i] - m; float sq = d[i]*d[i]; q += (double)sq; }
        #pragma unroll
        for (int o = 1; o < 64; o <<= 1) q += __shfl_xor(q, o, 64);
        q = __shfl(q, 0, 64);
        float var = (float)(q / 768.0);
        float inv = 1.0f / __fsqrt_rn(var + LN_EPS);
        #pragma unroll
        for (int i = 0; i < 12; ++i) {
            float yn = ((d[i] * inv) * gv[i]) + bv[i];
            v[i] += yn;
            fl = fl || (fabsf(v[i] - 1.0f) < TAU);
            bool sp = (v[i] >= 1.0f);
            Sp[base + lane + 64*i] = sp ? (u8)1 : (u8)0;
            if (sp) v[i] = 0.f;
        }
    }
    u64 bal = __ballot(fl);
    if (lane == 0 && bal != 0ull) flag[row] = 1;
}

// ---- repair flagged rows: exact bit-sequential GEMM, float4 + deep ILP ----
// 192 threads; thread c owns columns 4c..4c+3, each an independent sequential
// f32 add chain over ascending set-bit k (== np sgemm arithmetic exactly).
__global__ __launch_bounds__(192)
void k_repair(const u64* __restrict__ Am,
              const float* __restrict__ wq, const float* __restrict__ wk,
              const float* __restrict__ wv,
              const float* __restrict__ gq, const float* __restrict__ bq,
              const float* __restrict__ gk, const float* __restrict__ bk,
              const float* __restrict__ gv, const float* __restrict__ bv,
              u8* __restrict__ Qs, u8* __restrict__ Ks, u8* __restrict__ Vs,
              const u8* __restrict__ flags) {
    #pragma clang fp contract(off)
    int mat = blockIdx.y;
    int bs = blockIdx.x;
    if (!flags[(size_t)mat * BS_ + bs]) return;
    const float* W = (mat == 0) ? wq : (mat == 1) ? wk : wv;
    const float* g = (mat == 0) ? gq : (mat == 1) ? gk : gv;
    const float* bb = (mat == 0) ? bq : (mat == 1) ? bk : bv;
    u8* Sp = (mat == 0) ? Qs : (mat == 1) ? Ks : Vs;
    const float4* Wv4 = (const float4*)W;     // row k = 192 float4s
    __shared__ double red[3];
    __shared__ u64 mword_s[12];
    __shared__ int pops_s[12];
    __shared__ int cnt_s;
    __shared__ u16 idxs[768];
    int c = threadIdx.x;                      // 0..191
    int wv_ = c >> 6, lane = c & 63;
    float4 gd = ((const float4*)g)[c];
    float4 bd = ((const float4*)bb)[c];
    float v0 = 0.f, v1 = 0.f, v2 = 0.f, v3 = 0.f;
    for (int t = 0; t < T_; ++t) {
        // build ascending set-bit index list in LDS (np's k order)
        if (c < 12) {
            u64 m = Am[((size_t)t * 12 + c) * BS_ + bs];
            mword_s[c] = m;
            pops_s[c] = __popcll(m);
        }
        __syncthreads();
        if (c < 12) {
            int off = 0;
            for (int j = 0; j < c; ++j) off += pops_s[j];
            u64 m = mword_s[c];
            int base = c * 64;
            while (m) {
                int kb = __builtin_ctzll(m);
                m &= m - 1;
                idxs[off++] = (u16)(base + kb);
            }
            if (c == 11) cnt_s = off;
        }
        __syncthreads();
        int cnt = cnt_s;
        float y0 = 0.f, y1 = 0.f, y2 = 0.f, y3 = 0.f;
        #pragma unroll 8
        for (int i = 0; i < cnt; ++i) {
            float4 w = Wv4[(size_t)idxs[i] * 192 + c];
            y0 += w.x; y1 += w.y; y2 += w.z; y3 += w.w;
        }
        // f64 LN over 768 columns
        double s = (double)y0 + (double)y1 + (double)y2 + (double)y3;
        #pragma unroll
        for (int o = 1; o < 64; o <<= 1) s += __shfl_xor(s, o, 64);
        if (lane == 0) red[wv_] = s;
        __syncthreads();
        double stot = red[0] + red[1] + red[2];
        float mean = (float)(stot / 768.0);
        float d0 = y0 - mean, d1 = y1 - mean, d2 = y2 - mean, d3 = y3 - mean;
        double q = (double)(d0*d0) + (double)(d1*d1) + (double)(d2*d2) + (double)(d3*d3);
        #pragma unroll
        for (int o = 1; o < 64; o <<= 1) q += __shfl_xor(q, o, 64);
        __syncthreads();
        if (lane == 0) red[wv_] = q;
        __syncthreads();
        double qtot = red[0] + red[1] + red[2];
        float var = (float)(qtot / 768.0);
        float inv = 1.0f / __fsqrt_rn(var + LN_EPS);
        uchar4 o4;
        {
            float yn = ((d0 * inv) * gd.x) + bd.x; v0 += yn;
            bool sp = (v0 >= 1.0f); o4.x = sp ? 1 : 0; if (sp) v0 = 0.f;
        }
        {
            float yn = ((d1 * inv) * gd.y) + bd.y; v1 += yn;
            bool sp = (v1 >= 1.0f); o4.y = sp ? 1 : 0; if (sp) v1 = 0.f;
        }
        {
            float yn = ((d2 * inv) * gd.z) + bd.z; v2 += yn;
            bool sp = (v2 >= 1.0f); o4.z = sp ? 1 : 0; if (sp) v2 = 0.f;
        }
        {
            float yn = ((d3 * inv) * gd.w) + bd.w; v3 += yn;
            bool sp = (v3 >= 1.0f); o4.w = sp ? 1 : 0; if (sp) v3 = 0.f;
        }
        *(uchar4*)(Sp + ((size_t)t * BS_ + bs) * D_ + c * 4) = o4;
        __syncthreads();
    }
}

// ---- QK column-dot over S (exact integer counts) ----
__global__ void k_qkred(const u8* __restrict__ Q, const u8* __restrict__ K,
                        float* __restrict__ QK) {
    int bid = blockIdx.x;           // T_*B_*32 = 1024 blocks, 192 threads
    int sg = bid & 31, tb = bid >> 5;
    int tid = threadIdx.x;
    int c4 = tid * 4;
    size_t base = (size_t)tb * S_ * D_ + (size_t)sg * 32 * D_;
    int acc[4] = {0, 0, 0, 0};
    for (int s = 0; s < 32; ++s) {
        uchar4 q = *(const uchar4*)(Q + base + (size_t)s * D_ + c4);
        uchar4 k = *(const uchar4*)(K + base + (size_t)s * D_ + c4);
        acc[0] += q.x & k.x; acc[1] += q.y & k.y; acc[2] += q.z & k.z; acc[3] += q.w & k.w;
    }
    float* dst = QK + (size_t)tb * D_ + c4;
    #pragma unroll
    for (int j = 0; j < 4; ++j) atomicAdd(dst + j, (float)acc[j]);
}

// ---- IF over T on QK counts (integer-exact) ----
__global__ void k_qkif(const float* __restrict__ QK, u8* __restrict__ QKs) {
    int i = blockIdx.x * 256 + threadIdx.x;     // 24 blocks
    float v = 0.f;
    for (int t = 0; t < T_; ++t) {
        v += QK[t * (B_ * D_) + i];
        bool s = (v >= 1.0f);
        QKs[t * (B_ * D_) + i] = s ? 1 : 0;
        if (s) v = 0.f;
    }
}

// ---- QKV = V * QKs -> bf16 {0,1} ----
__global__ void k_qkv(const u8* __restrict__ V, const u8* __restrict__ QKs,
                      u16* __restrict__ O) {
    size_t e = ((size_t)blockIdx.x * 256 + threadIdx.x) * 4;    // 24576 blocks
    uchar4 v = *(const uchar4*)(V + e);
    size_t d = e % D_;
    size_t b = (e / ((size_t)S_ * D_)) % B_;
    size_t t = e / BSD_;
    uchar4 qk = *(const uchar4*)(QKs + t * (B_ * D_) + b * D_ + d);
    ushort4 o;
    o.x = (v.x & qk.x) ? 0x3F80 : 0;
    o.y = (v.y & qk.y) ? 0x3F80 : 0;
    o.z = (v.z & qk.z) ? 0x3F80 : 0;
    o.w = (v.w & qk.w) ? 0x3F80 : 0;
    *(ushort4*)(O + e) = o;
}

// ---- block reduction helper (final LN only; tolerance loose) ----
__device__ __forceinline__ float block_sum(float v, float* red) {
    #pragma unroll
    for (int o = 32; o > 0; o >>= 1) v += __shfl_down(v, o, 64);
    int lane = threadIdx.x & 63, w = threadIdx.x >> 6;
    __syncthreads();
    if (lane == 0) red[w] = v;
    __syncthreads();
    return (red[0] + red[1]) + (red[2] + red[3]);
}

__global__ __launch_bounds__(256)
void k_lnfinal(const float* __restrict__ Y, const float* __restrict__ g,
               const float* __restrict__ bt, float* __restrict__ out) {
    #pragma clang fp contract(off)
    __shared__ float red[4];
    size_t row = (size_t)blockIdx.x * D_;       // 32768 rows
    int tid = threadIdx.x;
    float y[3];
    float s = 0.f;
    #pragma unroll
    for (int j = 0; j < 3; ++j) { y[j] = Y[row + tid + j * 256]; s += y[j]; }
    float mean = block_sum(s, red) / 768.0f;
    float q = 0.f;
    #pragma unroll
    for (int j = 0; j < 3; ++j) { float d = y[j] - mean; q += d * d; }
    float var = block_sum(q, red) / 768.0f;
    float inv = 1.0f / __fsqrt_rn(var + LN_EPS);
    #pragma unroll
    for (int j = 0; j < 3; ++j) {
        int c = tid + j * 256;
        out[row + c] = (y[j] - mean) * inv * g[c] + bt[c];
    }
}

extern "C" void kernel_launch(void* const* d_in, const int* in_sizes, int n_in,
                              void* d_out, int out_size, void* d_ws, size_t ws_size,
                              hipStream_t stream) {
    const float* x  = (const float*)d_in[0];
    const float* wq = (const float*)d_in[1];
    const float* wk = (const float*)d_in[2];
    const float* wv = (const float*)d_in[3];
    const float* wo = (const float*)d_in[4];
    const float* gq = (const float*)d_in[5];
    const float* bq = (const float*)d_in[6];
    const float* gk = (const float*)d_in[7];
    const float* bk = (const float*)d_in[8];
    const float* gv = (const float*)d_in[9];
    const float* bv = (const float*)d_in[10];
    const float* go = (const float*)d_in[11];
    const float* bo = (const float*)d_in[12];
    float* out = (float*)d_out;

    char* ws = (char*)d_ws;
    size_t off = 0;
    auto alloc = [&](size_t bytes) -> void* {
        void* p = ws + off;
        off += (bytes + 255) & ~(size_t)255;
        return p;
    };
    u64* Am    = (u64*)alloc((size_t)T_ * 12 * BS_ * 8);     // 3 MB bitmasks
    u16* Ab    = (u16*)alloc((size_t)M_ * D_ * 2);           // 48 MB bf16 spikes / reused for QKV
    float* Y   = (float*)alloc((size_t)M_ * D_ * 4);         // 96 MB GEMM out
    u8* Qs     = (u8*)alloc((size_t)M_ * D_);
    u8* Ks     = (u8*)alloc((size_t)M_ * D_);
    u8* Vs     = (u8*)alloc((size_t)M_ * D_);
    u16* Whi   = (u16*)alloc((size_t)3 * D_ * D_ * 2);
    u16* Wlo   = (u16*)alloc((size_t)3 * D_ * D_ * 2);
    u16* Wo    = (u16*)alloc((size_t)D_ * D_ * 2);
    float* QK  = (float*)alloc((size_t)T_ * B_ * D_ * 4);
    u8* QKs    = (u8*)alloc((size_t)T_ * B_ * D_);
    u8* flags  = (u8*)alloc((size_t)3 * BS_);

    hipMemsetAsync(QK, 0, (size_t)T_ * B_ * D_ * 4, stream);
    hipMemsetAsync(flags, 0, (size_t)3 * BS_, stream);

    // 1. IF over x -> bitmasks + bf16 spikes (bit-exact)
    k_if_mask<<<BS_, 768, 0, stream>>>(x, Am, Ab);
    // 2. weight conversion
    k_wconv<<<(4 * D_ * D_) / 256, 256, 0, stream>>>(wq, wk, wv, wo, Whi, Wlo, Wo);
    // 3. Q/K/V: split-bf16 MFMA GEMM + f64-LN + IF + boundary flags
    const int ntn = D_ / 128;                           // 6
    const int gemm_grid = (M_ / 128) * ntn;             // 1536
    k_gemm<2><<<gemm_grid, 256, 0, stream>>>(Ab, Whi + 0 * D_ * D_, Wlo + 0 * D_ * D_, Y, ntn, D_);
    k_lnif<<<BS_ / 4, 256, 0, stream>>>(Y, gq, bq, Qs, flags + 0 * BS_);
    k_gemm<2><<<gemm_grid, 256, 0, stream>>>(Ab, Whi + 1 * D_ * D_, Wlo + 1 * D_ * D_, Y, ntn, D_);
    k_lnif<<<BS_ / 4, 256, 0, stream>>>(Y, gk, bk, Ks, flags + 1 * BS_);
    k_gemm<2><<<gemm_grid, 256, 0, stream>>>(Ab, Whi + 2 * D_ * D_, Wlo + 2 * D_ * D_, Y, ntn, D_);
    k_lnif<<<BS_ / 4, 256, 0, stream>>>(Y, gv, bv, Vs, flags + 2 * BS_);
    // 3b. exact repair of boundary-flagged rows (reproduces np arithmetic)
    k_repair<<<dim3(BS_, 3), 192, 0, stream>>>(Am, wq, wk, wv, gq, bq, gk, bk, gv, bv,
                                               Qs, Ks, Vs, flags);
    // 4. QK column-dot + IF (integer-exact)
    k_qkred<<<T_ * B_ * 32, 192, 0, stream>>>(Qs, Ks, QK);
    k_qkif<<<(B_ * D_) / 256, 256, 0, stream>>>(QK, QKs);
    // 5. QKV = V * QKs -> bf16 (reuse Ab)
    k_qkv<<<(M_ * D_) / 4 / 256, 256, 0, stream>>>(Vs, QKs, Ab);
    // 6. output projection (bf16 MFMA; loose tolerance) + final LN
    k_gemm<1><<<gemm_grid, 256, 0, stream>>>(Ab, Wo, Wo, Y, ntn, D_);
    k_lnfinal<<<M_, 256, 0, stream>>>(Y, go, bo, out);
}

// Round 6
// 652.693 us; speedup vs baseline: 4.7841x; 1.2043x over previous
//
#include <hip/hip_runtime.h>
#include <hip/hip_bf16.h>

#define T_ 4
#define B_ 8
#define S_ 1024
#define D_ 768
#define BS_ (B_*S_)            // 8192
#define M_ (T_*B_*S_)          // 32768
#define BSD_ (B_*S_*D_)        // 6291456
#define LN_EPS 1e-5f
#define TAU 4e-5f

typedef unsigned short u16;
typedef unsigned char u8;
typedef unsigned long long u64;
typedef __bf16 bf16x8 __attribute__((ext_vector_type(8)));
typedef float f32x4 __attribute__((ext_vector_type(4)));

// ---- IF over x -> bitmask spikes + bf16 spikes, bit-exact vs np ----
__global__ __launch_bounds__(768)
void k_if_mask(const float* __restrict__ x, u64* __restrict__ Am, u16* __restrict__ Ab) {
    int bs = blockIdx.x;           // 8192 blocks
    int d = threadIdx.x;           // 768 threads
    int wv = d >> 6, lane = d & 63;
    float v = 0.f;
    for (int t = 0; t < T_; ++t) {
        v += x[(size_t)t * BSD_ + (size_t)bs * D_ + d];
        bool s = (v >= 1.0f);
        u64 m = __ballot(s);
        if (lane == 0) Am[((size_t)t * 12 + wv) * BS_ + bs] = m;
        Ab[(size_t)t * BSD_ + (size_t)bs * D_ + d] = s ? 0x3F80 : 0;
        if (s) v = 0.f;
    }
}

// ---- weight convert: Bt layout [N][K], hi/lo split for q/k/v; bf16 for wo ----
__global__ void k_wconv(const float* __restrict__ wq, const float* __restrict__ wk,
                        const float* __restrict__ wv, const float* __restrict__ wo,
                        u16* __restrict__ Whi, u16* __restrict__ Wlo, u16* __restrict__ Wo) {
    int idx = blockIdx.x * 256 + threadIdx.x;       // 9216 blocks
    int mat = idx / (D_ * D_);
    int r = idx % (D_ * D_);
    int n = r / D_;
    int k = r % D_;
    const float* src = (mat == 0) ? wq : (mat == 1) ? wk : (mat == 2) ? wv : wo;
    float w = src[k * D_ + n];
    __bf16 hi = (__bf16)w;
    u16 uhi = __builtin_bit_cast(u16, hi);
    if (mat == 3) { Wo[r] = uhi; return; }
    float lo = w - (float)hi;
    u16 ulo = __builtin_bit_cast(u16, (__bf16)lo);
    Whi[(size_t)mat * D_ * D_ + r] = uhi;
    Wlo[(size_t)mat * D_ * D_ + r] = ulo;
}

// ---- MFMA GEMM: C = A @ Bhi^T (+ A @ Blo^T if NMATS==2), single K pass ----
// LDS chunk-XOR swizzle: involution C' = C ^ ((C>>3)&3) permutes the four
// 16B chunks within each 64B row; staging uses pre-swizzled source column,
// reads use kh ^ ((lan16>>1)&3). Spreads quarter-wave ds_read_b128 across
// all 8 bank groups (2 lanes each -> conflict-free).
__device__ __forceinline__ void gload16(const void* g, void* l) {
    __builtin_amdgcn_global_load_lds(
        (const __attribute__((address_space(1))) unsigned int*)g,
        (__attribute__((address_space(3))) unsigned int*)l, 16, 0, 0);
}

template<int NMATS>
__global__ __launch_bounds__(256)
void k_gemm(const u16* __restrict__ A, const u16* __restrict__ Bhi,
            const u16* __restrict__ Blo, float* __restrict__ C, int ntn, int N) {
    __shared__ __align__(16) u16 As[128 * 32];
    __shared__ __align__(16) u16 Bh[128 * 32];
    __shared__ __align__(16) u16 Bl[128 * 32];
    int bid = blockIdx.x;
    bid = (bid & 7) * (gridDim.x >> 3) + (bid >> 3);   // XCD chunked swizzle (grid%8==0)
    int bn = bid % ntn, bm = bid / ntn;
    int tid = threadIdx.x;
    int l = tid & 63, w = tid >> 6;
    int wr = w >> 1, wc = w & 1;
    int lan16 = l & 15, kh = l >> 4;

    f32x4 acc[4][4];
    #pragma unroll
    for (int m = 0; m < 4; ++m)
        #pragma unroll
        for (int n = 0; n < 4; ++n)
            #pragma unroll
            for (int r = 0; r < 4; ++r) acc[m][n][r] = 0.f;

    int arow = bm * 128 + (tid >> 2);
    int brow = bn * 128 + (tid >> 2);
    int colb = (((tid & 3) ^ ((tid >> 3) & 3)) * 8);   // pre-swizzled source chunk
    char* ldsA = (char*)As + ((tid >> 6) << 10);
    char* ldsBh = (char*)Bh + ((tid >> 6) << 10);
    char* ldsBl = (char*)Bl + ((tid >> 6) << 10);

    int khs16 = (kh ^ ((lan16 >> 1) & 3)) << 4;        // swizzled read chunk byte
    int aoff[4], boff[4];
    #pragma unroll
    for (int m = 0; m < 4; ++m) aoff[m] = (wr * 64 + m * 16 + lan16) * 64 + khs16;
    #pragma unroll
    for (int n = 0; n < 4; ++n) boff[n] = (wc * 64 + n * 16 + lan16) * 64 + khs16;

    for (int kk = 0; kk < 768; kk += 32) {
        gload16(A   + (size_t)(arow     ) * 768 + kk + colb, ldsA);
        gload16(A   + (size_t)(arow + 64) * 768 + kk + colb, ldsA + 4096);
        gload16(Bhi + (size_t)(brow     ) * 768 + kk + colb, ldsBh);
        gload16(Bhi + (size_t)(brow + 64) * 768 + kk + colb, ldsBh + 4096);
        if (NMATS == 2) {
            gload16(Blo + (size_t)(brow     ) * 768 + kk + colb, ldsBl);
            gload16(Blo + (size_t)(brow + 64) * 768 + kk + colb, ldsBl + 4096);
        }
        __syncthreads();
        bf16x8 af[4], bh[4], bl[4];
        #pragma unroll
        for (int m = 0; m < 4; ++m)
            af[m] = *(const bf16x8*)((const char*)As + aoff[m]);
        #pragma unroll
        for (int n = 0; n < 4; ++n) {
            bh[n] = *(const bf16x8*)((const char*)Bh + boff[n]);
            if (NMATS == 2) bl[n] = *(const bf16x8*)((const char*)Bl + boff[n]);
        }
        #pragma unroll
        for (int m = 0; m < 4; ++m)
            #pragma unroll
            for (int n = 0; n < 4; ++n) {
                acc[m][n] = __builtin_amdgcn_mfma_f32_16x16x32_bf16(af[m], bh[n], acc[m][n], 0, 0, 0);
                if (NMATS == 2)
                    acc[m][n] = __builtin_amdgcn_mfma_f32_16x16x32_bf16(af[m], bl[n], acc[m][n], 0, 0, 0);
            }
        __syncthreads();
    }
    #pragma unroll
    for (int m = 0; m < 4; ++m)
        #pragma unroll
        for (int n = 0; n < 4; ++n)
            #pragma unroll
            for (int r = 0; r < 4; ++r) {
                int crow = bm * 128 + wr * 64 + m * 16 + kh * 4 + r;
                int ccol = bn * 128 + wc * 64 + n * 16 + lan16;
                C[(size_t)crow * N + ccol] = acc[m][n][r];
            }
}

// ---- LN (f64 mean/var) + IF -> u8 spikes, with boundary-margin flagging ----
__global__ __launch_bounds__(256)
void k_lnif(const float* __restrict__ Y, const float* __restrict__ g,
            const float* __restrict__ bt, u8* __restrict__ Sp, u8* __restrict__ flag) {
    #pragma clang fp contract(off)
    int row = blockIdx.x * 4 + (threadIdx.x >> 6);   // (b,s) 0..8191
    int lane = threadIdx.x & 63;
    float v[12];
    #pragma unroll
    for (int i = 0; i < 12; ++i) v[i] = 0.f;
    float gv[12], bv[12];
    #pragma unroll
    for (int i = 0; i < 12; ++i) { gv[i] = g[lane + 64*i]; bv[i] = bt[lane + 64*i]; }
    bool fl = false;
    for (int t = 0; t < T_; ++t) {
        size_t base = ((size_t)t * BS_ + row) * D_;
        float xv[12];
        double s = 0.0;
        #pragma unroll
        for (int i = 0; i < 12; ++i) { xv[i] = Y[base + lane + 64*i]; s += (double)xv[i]; }
        #pragma unroll
        for (int o = 1; o < 64; o <<= 1) s += __shfl_xor(s, o, 64);
        s = __shfl(s, 0, 64);
        float m = (float)(s / 768.0);
        float d[12];
        double q = 0.0;
        #pragma unroll
        for (int i = 0; i < 12; ++i) { d[i] = xv[i] - m; float sq = d[i]*d[i]; q += (double)sq; }
        #pragma unroll
        for (int o = 1; o < 64; o <<= 1) q += __shfl_xor(q, o, 64);
        q = __shfl(q, 0, 64);
        float var = (float)(q / 768.0);
        float inv = 1.0f / __fsqrt_rn(var + LN_EPS);
        #pragma unroll
        for (int i = 0; i < 12; ++i) {
            float yn = ((d[i] * inv) * gv[i]) + bv[i];
            v[i] += yn;
            fl = fl || (fabsf(v[i] - 1.0f) < TAU);
            bool sp = (v[i] >= 1.0f);
            Sp[base + lane + 64*i] = sp ? (u8)1 : (u8)0;
            if (sp) v[i] = 0.f;
        }
    }
    u64 bal = __ballot(fl);
    if (lane == 0 && bal != 0ull) flag[row] = 1;
}

// ---- repair flagged rows: exact bit-sequential GEMM, float4 + deep ILP ----
__global__ __launch_bounds__(192)
void k_repair(const u64* __restrict__ Am,
              const float* __restrict__ wq, const float* __restrict__ wk,
              const float* __restrict__ wv,
              const float* __restrict__ gq, const float* __restrict__ bq,
              const float* __restrict__ gk, const float* __restrict__ bk,
              const float* __restrict__ gv, const float* __restrict__ bv,
              u8* __restrict__ Qs, u8* __restrict__ Ks, u8* __restrict__ Vs,
              const u8* __restrict__ flags) {
    #pragma clang fp contract(off)
    int mat = blockIdx.y;
    int bs = blockIdx.x;
    if (!flags[(size_t)mat * BS_ + bs]) return;
    const float* W = (mat == 0) ? wq : (mat == 1) ? wk : wv;
    const float* g = (mat == 0) ? gq : (mat == 1) ? gk : gv;
    const float* bb = (mat == 0) ? bq : (mat == 1) ? bk : bv;
    u8* Sp = (mat == 0) ? Qs : (mat == 1) ? Ks : Vs;
    const float4* Wv4 = (const float4*)W;     // row k = 192 float4s
    __shared__ double red[3];
    __shared__ u64 mword_s[12];
    __shared__ int pops_s[12];
    __shared__ int cnt_s;
    __shared__ u16 idxs[768];
    int c = threadIdx.x;                      // 0..191
    int wv_ = c >> 6, lane = c & 63;
    float4 gd = ((const float4*)g)[c];
    float4 bd = ((const float4*)bb)[c];
    float v0 = 0.f, v1 = 0.f, v2 = 0.f, v3 = 0.f;
    for (int t = 0; t < T_; ++t) {
        if (c < 12) {
            u64 m = Am[((size_t)t * 12 + c) * BS_ + bs];
            mword_s[c] = m;
            pops_s[c] = __popcll(m);
        }
        __syncthreads();
        if (c < 12) {
            int off = 0;
            for (int j = 0; j < c; ++j) off += pops_s[j];
            u64 m = mword_s[c];
            int base = c * 64;
            while (m) {
                int kb = __builtin_ctzll(m);
                m &= m - 1;
                idxs[off++] = (u16)(base + kb);
            }
            if (c == 11) cnt_s = off;
        }
        __syncthreads();
        int cnt = cnt_s;
        float y0 = 0.f, y1 = 0.f, y2 = 0.f, y3 = 0.f;
        #pragma unroll 8
        for (int i = 0; i < cnt; ++i) {
            float4 w = Wv4[(size_t)idxs[i] * 192 + c];
            y0 += w.x; y1 += w.y; y2 += w.z; y3 += w.w;
        }
        double s = (double)y0 + (double)y1 + (double)y2 + (double)y3;
        #pragma unroll
        for (int o = 1; o < 64; o <<= 1) s += __shfl_xor(s, o, 64);
        if (lane == 0) red[wv_] = s;
        __syncthreads();
        double stot = red[0] + red[1] + red[2];
        float mean = (float)(stot / 768.0);
        float d0 = y0 - mean, d1 = y1 - mean, d2 = y2 - mean, d3 = y3 - mean;
        double q = (double)(d0*d0) + (double)(d1*d1) + (double)(d2*d2) + (double)(d3*d3);
        #pragma unroll
        for (int o = 1; o < 64; o <<= 1) q += __shfl_xor(q, o, 64);
        __syncthreads();
        if (lane == 0) red[wv_] = q;
        __syncthreads();
        double qtot = red[0] + red[1] + red[2];
        float var = (float)(qtot / 768.0);
        float inv = 1.0f / __fsqrt_rn(var + LN_EPS);
        uchar4 o4;
        {
            float yn = ((d0 * inv) * gd.x) + bd.x; v0 += yn;
            bool sp = (v0 >= 1.0f); o4.x = sp ? 1 : 0; if (sp) v0 = 0.f;
        }
        {
            float yn = ((d1 * inv) * gd.y) + bd.y; v1 += yn;
            bool sp = (v1 >= 1.0f); o4.y = sp ? 1 : 0; if (sp) v1 = 0.f;
        }
        {
            float yn = ((d2 * inv) * gd.z) + bd.z; v2 += yn;
            bool sp = (v2 >= 1.0f); o4.z = sp ? 1 : 0; if (sp) v2 = 0.f;
        }
        {
            float yn = ((d3 * inv) * gd.w) + bd.w; v3 += yn;
            bool sp = (v3 >= 1.0f); o4.w = sp ? 1 : 0; if (sp) v3 = 0.f;
        }
        *(uchar4*)(Sp + ((size_t)t * BS_ + bs) * D_ + c * 4) = o4;
        __syncthreads();
    }
}

// ---- QK column-dot over S (exact integer counts) ----
__global__ void k_qkred(const u8* __restrict__ Q, const u8* __restrict__ K,
                        float* __restrict__ QK) {
    int bid = blockIdx.x;           // T_*B_*32 = 1024 blocks, 192 threads
    int sg = bid & 31, tb = bid >> 5;
    int tid = threadIdx.x;
    int c4 = tid * 4;
    size_t base = (size_t)tb * S_ * D_ + (size_t)sg * 32 * D_;
    int acc[4] = {0, 0, 0, 0};
    for (int s = 0; s < 32; ++s) {
        uchar4 q = *(const uchar4*)(Q + base + (size_t)s * D_ + c4);
        uchar4 k = *(const uchar4*)(K + base + (size_t)s * D_ + c4);
        acc[0] += q.x & k.x; acc[1] += q.y & k.y; acc[2] += q.z & k.z; acc[3] += q.w & k.w;
    }
    float* dst = QK + (size_t)tb * D_ + c4;
    #pragma unroll
    for (int j = 0; j < 4; ++j) atomicAdd(dst + j, (float)acc[j]);
}

// ---- IF over T on QK counts (integer-exact) ----
__global__ void k_qkif(const float* __restrict__ QK, u8* __restrict__ QKs) {
    int i = blockIdx.x * 256 + threadIdx.x;     // 24 blocks
    float v = 0.f;
    for (int t = 0; t < T_; ++t) {
        v += QK[t * (B_ * D_) + i];
        bool s = (v >= 1.0f);
        QKs[t * (B_ * D_) + i] = s ? 1 : 0;
        if (s) v = 0.f;
    }
}

// ---- QKV = V * QKs -> bf16 {0,1} ----
__global__ void k_qkv(const u8* __restrict__ V, const u8* __restrict__ QKs,
                      u16* __restrict__ O) {
    size_t e = ((size_t)blockIdx.x * 256 + threadIdx.x) * 4;    // 24576 blocks
    uchar4 v = *(const uchar4*)(V + e);
    size_t d = e % D_;
    size_t b = (e / ((size_t)S_ * D_)) % B_;
    size_t t = e / BSD_;
    uchar4 qk = *(const uchar4*)(QKs + t * (B_ * D_) + b * D_ + d);
    ushort4 o;
    o.x = (v.x & qk.x) ? 0x3F80 : 0;
    o.y = (v.y & qk.y) ? 0x3F80 : 0;
    o.z = (v.z & qk.z) ? 0x3F80 : 0;
    o.w = (v.w & qk.w) ? 0x3F80 : 0;
    *(ushort4*)(O + e) = o;
}

// ---- block reduction helper (final LN only; tolerance loose) ----
__device__ __forceinline__ float block_sum(float v, float* red) {
    #pragma unroll
    for (int o = 32; o > 0; o >>= 1) v += __shfl_down(v, o, 64);
    int lane = threadIdx.x & 63, w = threadIdx.x >> 6;
    __syncthreads();
    if (lane == 0) red[w] = v;
    __syncthreads();
    return (red[0] + red[1]) + (red[2] + red[3]);
}

__global__ __launch_bounds__(256)
void k_lnfinal(const float* __restrict__ Y, const float* __restrict__ g,
               const float* __restrict__ bt, float* __restrict__ out) {
    #pragma clang fp contract(off)
    __shared__ float red[4];
    size_t row = (size_t)blockIdx.x * D_;       // 32768 rows
    int tid = threadIdx.x;
    float y[3];
    float s = 0.f;
    #pragma unroll
    for (int j = 0; j < 3; ++j) { y[j] = Y[row + tid + j * 256]; s += y[j]; }
    float mean = block_sum(s, red) / 768.0f;
    float q = 0.f;
    #pragma unroll
    for (int j = 0; j < 3; ++j) { float d = y[j] - mean; q += d * d; }
    float var = block_sum(q, red) / 768.0f;
    float inv = 1.0f / __fsqrt_rn(var + LN_EPS);
    #pragma unroll
    for (int j = 0; j < 3; ++j) {
        int c = tid + j * 256;
        out[row + c] = (y[j] - mean) * inv * g[c] + bt[c];
    }
}

extern "C" void kernel_launch(void* const* d_in, const int* in_sizes, int n_in,
                              void* d_out, int out_size, void* d_ws, size_t ws_size,
                              hipStream_t stream) {
    const float* x  = (const float*)d_in[0];
    const float* wq = (const float*)d_in[1];
    const float* wk = (const float*)d_in[2];
    const float* wv = (const float*)d_in[3];
    const float* wo = (const float*)d_in[4];
    const float* gq = (const float*)d_in[5];
    const float* bq = (const float*)d_in[6];
    const float* gk = (const float*)d_in[7];
    const float* bk = (const float*)d_in[8];
    const float* gv = (const float*)d_in[9];
    const float* bv = (const float*)d_in[10];
    const float* go = (const float*)d_in[11];
    const float* bo = (const float*)d_in[12];
    float* out = (float*)d_out;

    char* ws = (char*)d_ws;
    size_t off = 0;
    auto alloc = [&](size_t bytes) -> void* {
        void* p = ws + off;
        off += (bytes + 255) & ~(size_t)255;
        return p;
    };
    u64* Am    = (u64*)alloc((size_t)T_ * 12 * BS_ * 8);     // 3 MB bitmasks
    u16* Ab    = (u16*)alloc((size_t)M_ * D_ * 2);           // 48 MB bf16 spikes / reused for QKV
    float* Y   = (float*)alloc((size_t)M_ * D_ * 4);         // 96 MB GEMM out
    u8* Qs     = (u8*)alloc((size_t)M_ * D_);
    u8* Ks     = (u8*)alloc((size_t)M_ * D_);
    u8* Vs     = (u8*)alloc((size_t)M_ * D_);
    u16* Whi   = (u16*)alloc((size_t)3 * D_ * D_ * 2);
    u16* Wlo   = (u16*)alloc((size_t)3 * D_ * D_ * 2);
    u16* Wo    = (u16*)alloc((size_t)D_ * D_ * 2);
    float* QK  = (float*)alloc((size_t)T_ * B_ * D_ * 4);
    u8* QKs    = (u8*)alloc((size_t)T_ * B_ * D_);
    u8* flags  = (u8*)alloc((size_t)3 * BS_);

    hipMemsetAsync(QK, 0, (size_t)T_ * B_ * D_ * 4, stream);
    hipMemsetAsync(flags, 0, (size_t)3 * BS_, stream);

    // 1. IF over x -> bitmasks + bf16 spikes (bit-exact)
    k_if_mask<<<BS_, 768, 0, stream>>>(x, Am, Ab);
    // 2. weight conversion
    k_wconv<<<(4 * D_ * D_) / 256, 256, 0, stream>>>(wq, wk, wv, wo, Whi, Wlo, Wo);
    // 3. Q/K/V: split-bf16 MFMA GEMM (single pass, hi+lo) + f64-LN + IF + flags
    const int ntn = D_ / 128;                           // 6
    const int gemm_grid = (M_ / 128) * ntn;             // 1536 (%8==0 for XCD swizzle)
    k_gemm<2><<<gemm_grid, 256, 0, stream>>>(Ab, Whi + 0 * D_ * D_, Wlo + 0 * D_ * D_, Y, ntn, D_);
    k_lnif<<<BS_ / 4, 256, 0, stream>>>(Y, gq, bq, Qs, flags + 0 * BS_);
    k_gemm<2><<<gemm_grid, 256, 0, stream>>>(Ab, Whi + 1 * D_ * D_, Wlo + 1 * D_ * D_, Y, ntn, D_);
    k_lnif<<<BS_ / 4, 256, 0, stream>>>(Y, gk, bk, Ks, flags + 1 * BS_);
    k_gemm<2><<<gemm_grid, 256, 0, stream>>>(Ab, Whi + 2 * D_ * D_, Wlo + 2 * D_ * D_, Y, ntn, D_);
    k_lnif<<<BS_ / 4, 256, 0, stream>>>(Y, gv, bv, Vs, flags + 2 * BS_);
    // 3b. exact repair of boundary-flagged rows (reproduces np arithmetic)
    k_repair<<<dim3(BS_, 3), 192, 0, stream>>>(Am, wq, wk, wv, gq, bq, gk, bk, gv, bv,
                                               Qs, Ks, Vs, flags);
    // 4. QK column-dot + IF (integer-exact)
    k_qkred<<<T_ * B_ * 32, 192, 0, stream>>>(Qs, Ks, QK);
    k_qkif<<<(B_ * D_) / 256, 256, 0, stream>>>(QK, QKs);
    // 5. QKV = V * QKs -> bf16 (reuse Ab)
    k_qkv<<<(M_ * D_) / 4 / 256, 256, 0, stream>>>(Vs, QKs, Ab);
    // 6. output projection (bf16 MFMA; loose tolerance) + final LN
    k_gemm<1><<<gemm_grid, 256, 0, stream>>>(Ab, Wo, Wo, Y, ntn, D_);
    k_lnfinal<<<M_, 256, 0, stream>>>(Y, go, bo, out);
}